// Round 6
// baseline (247.734 us; speedup 1.0000x reference)
//
#include <hip/hip_runtime.h>
#include <hip/hip_bf16.h>

#define B_   16
#define T_   128
#define IN_  1024
#define H_   4096
#define OUT_ 1024
#define M_   (B_ * T_)   // 2048 rows = (b*T + t)

typedef __attribute__((ext_vector_type(8))) short short8;
typedef __attribute__((ext_vector_type(4))) float f32x4;
typedef __attribute__((ext_vector_type(4))) int i32x4;
typedef __attribute__((ext_vector_type(4))) unsigned short u16x4;
typedef unsigned short u16;
typedef signed char i8;

// ---------- helpers ----------
__device__ inline u16 f2bf_rne(float f) {
  unsigned u = __float_as_uint(f);
  unsigned r = u + 0x7FFFu + ((u >> 16) & 1u);
  return (u16)(r >> 16);
}
__device__ inline float bf2f(u16 s) {
  return __uint_as_float(((unsigned)s) << 16);
}
__device__ inline int pack4(int a, int b, int c, int d) {
  return (a & 255) | ((b & 255) << 8) | ((c & 255) << 16) | ((d & 255) << 24);
}

// XCD-aware 2D-chunked bijective swizzle (T1) for 512-block grids.
__device__ inline void xcd_swizzle(int bid0, int& bnI, int& bmI) {
  const int xcd = bid0 & 7;
  const int loc = bid0 >> 3;           // 0..63 within XCD
  bnI = (xcd & 3) * 8 + (loc & 7);
  bmI = (xcd >> 2) * 8 + (loc >> 3);
}

#define NX_  (M_ * IN_)
#define NW1_ (H_ * IN_)
#define NW2_ (H_ * H_)

__device__ inline void split4bf(const float4 f, u16* __restrict__ hi,
                                u16* __restrict__ lo, size_t e) {
  u16x4 h, l;
  h.x = f2bf_rne(f.x); l.x = f2bf_rne(f.x - bf2f(h.x));
  h.y = f2bf_rne(f.y); l.y = f2bf_rne(f.y - bf2f(h.y));
  h.z = f2bf_rne(f.z); l.z = f2bf_rne(f.z - bf2f(h.z));
  h.w = f2bf_rne(f.w); l.w = f2bf_rne(f.w - bf2f(h.w));
  *(u16x4*)(hi + e) = h;
  *(u16x4*)(lo + e) = l;
}

__device__ inline void splitw2_1(float w, int& c0, int& c1, int& c2) {
  int wf = __float2int_rn(w * 268435456.0f);  // 2^28 (exact: wf == c0<<16 + c1<<8 + c2)
  c0 = (wf + 32768) >> 16;
  int r0 = wf - (c0 << 16);
  if (r0 >= 32640) { c0 += 1; r0 -= 65536; }
  c1 = (r0 + 128) >> 8;
  c2 = r0 - (c1 << 8);
}

// ---------- split x, w1 only (w2 split is woven into gemm1) ----------
__global__ void split_xw1_kernel(const float4* __restrict__ x,
                                 const float4* __restrict__ w1,
                                 u16* __restrict__ xh, u16* __restrict__ xl,
                                 u16* __restrict__ w1h, u16* __restrict__ w1l) {
  const int total4 = (NX_ + NW1_) / 4;
  for (int i = blockIdx.x * blockDim.x + threadIdx.x; i < total4;
       i += gridDim.x * blockDim.x) {
    if (i < NX_ / 4) {
      split4bf(x[i], xh, xl, (size_t)i * 4);
    } else {
      int j = i - NX_ / 4;
      split4bf(w1[j], w1h, w1l, (size_t)j * 4);
    }
  }
}

// ---------- GEMM1: FUSED 4-combo bf16 (16x16x32, BK=64) + rec1 -> s1 (i8) ----------
// (unchanged — isolate the gemm2 A-direct change)
#define BK1 64

__global__ __launch_bounds__(256, 2) void gemm1_rec(
    const u16* __restrict__ Ah, const u16* __restrict__ Al,
    const u16* __restrict__ Bh, const u16* __restrict__ Bl,
    const float* __restrict__ bias, i8* __restrict__ s1out,
    const float4* __restrict__ w2src,
    i8* __restrict__ p0, i8* __restrict__ p1, i8* __restrict__ p2) {
  __shared__ __align__(16) char smem[65536];   // sAh|sAl|sBh|sBl 16K each; epilogue reuses [0,32K)
  u16* sAh = (u16*)smem;
  u16* sAl = (u16*)(smem + 16384);
  u16* sBh = (u16*)(smem + 32768);
  u16* sBl = (u16*)(smem + 49152);

  const int tid  = threadIdx.x;
  const int lane = tid & 63;
  const int wid  = tid >> 6;
  const int wm   = (wid >> 1) * 64;
  const int wn   = (wid & 1) * 64;
  const int bid  = blockIdx.y * 32 + blockIdx.x;   // flat id: w2-slice owner
  int bnI, bmI;
  xcd_swizzle(bid, bnI, bmI);
  const int bm = bmI * 128;
  const int bn = bnI * 128;

  const int sdst = (tid & 7) * 8;                          // linear LDS dest slot (elems)
  const int scol = (((tid & 7) ^ ((tid >> 3) & 7)) * 8);   // inverse-swizzled src col
  const int q8   = (lane >> 4) * 8;
  const int rsw  = (lane & 7) * 8;                         // row&7 == lane&7 swizzle

  f32x4 acc[4][4];
#pragma unroll
  for (int i = 0; i < 4; ++i)
#pragma unroll
    for (int j = 0; j < 4; ++j) acc[i][j] = (f32x4){0.f, 0.f, 0.f, 0.f};

  // woven-split pipeline prologue: tile 0's slice into regs
  const int wbase = bid * 8192 + tid * 2;
  float4 wfa = w2src[wbase];
  float4 wfb = w2src[wbase + 1];

#pragma unroll 1
  for (int it = 0; it < IN_ / BK1; ++it) {   // 16 k-tiles
    const int kt = it * BK1;
    __syncthreads();   // bar1: wf prefetch + stores from prev iter long done
#pragma unroll
    for (int l = 0; l < 4; ++l) {
      int row = l * 32 + (tid >> 3);
      size_t ga = (size_t)(bm + row) * IN_ + kt + scol;
      size_t gb = (size_t)(bn + row) * IN_ + kt + scol;
      int ld = row * BK1 + sdst;
      __builtin_amdgcn_global_load_lds(
          (const __attribute__((address_space(1))) unsigned int*)(Ah + ga),
          (__attribute__((address_space(3))) unsigned int*)(&sAh[ld]), 16, 0, 0);
      __builtin_amdgcn_global_load_lds(
          (const __attribute__((address_space(1))) unsigned int*)(Al + ga),
          (__attribute__((address_space(3))) unsigned int*)(&sAl[ld]), 16, 0, 0);
      __builtin_amdgcn_global_load_lds(
          (const __attribute__((address_space(1))) unsigned int*)(Bh + gb),
          (__attribute__((address_space(3))) unsigned int*)(&sBh[ld]), 16, 0, 0);
      __builtin_amdgcn_global_load_lds(
          (const __attribute__((address_space(1))) unsigned int*)(Bl + gb),
          (__attribute__((address_space(3))) unsigned int*)(&sBl[ld]), 16, 0, 0);
    }
    __syncthreads();   // bar2: drains ONLY L2-resident staging loads now

    // prefetch NEXT tile's wf slice (covered by the MFMA phase below)
    const int nit = (it + 1 < 16) ? it + 1 : 15;
    float4 nfa = w2src[wbase + nit * 512];
    float4 nfb = w2src[wbase + nit * 512 + 1];

    // convert + store CURRENT tile's wf (independent of MFMA; drains in bg)
    {
      const int sbase = bid * 8192 + it * 512 + tid * 2;
#pragma unroll
      for (int u = 0; u < 2; ++u) {
        float4 f = u ? wfb : wfa;
        int a0, a1, a2, b0, b1, b2, c0, c1, c2, d0, d1, d2;
        splitw2_1(f.x, a0, a1, a2);
        splitw2_1(f.y, b0, b1, b2);
        splitw2_1(f.z, c0, c1, c2);
        splitw2_1(f.w, d0, d1, d2);
        size_t e = (size_t)(sbase + u) * 4;
        *(int*)(p0 + e) = pack4(a0, b0, c0, d0);
        *(int*)(p1 + e) = pack4(a1, b1, c1, d1);
        *(int*)(p2 + e) = pack4(a2, b2, c2, d2);
      }
    }

#pragma unroll
    for (int ks = 0; ks < BK1; ks += 32) {
      const int swz = (ks + q8) ^ rsw;
      short8 ah[4], al[4], bh[4], bl[4];
#pragma unroll
      for (int i = 0; i < 4; ++i) {
        int ro = (wm + i * 16 + (lane & 15)) * BK1 + swz;
        ah[i] = *(const short8*)&sAh[ro];
        al[i] = *(const short8*)&sAl[ro];
      }
#pragma unroll
      for (int j = 0; j < 4; ++j) {
        int ro = (wn + j * 16 + (lane & 15)) * BK1 + swz;
        bh[j] = *(const short8*)&sBh[ro];
        bl[j] = *(const short8*)&sBl[ro];
      }
#pragma unroll
      for (int i = 0; i < 4; ++i)
#pragma unroll
        for (int j = 0; j < 4; ++j) {
          acc[i][j] = __builtin_amdgcn_mfma_f32_16x16x32_bf16(ah[i], bh[j], acc[i][j], 0, 0, 0);
          acc[i][j] = __builtin_amdgcn_mfma_f32_16x16x32_bf16(ah[i], bl[j], acc[i][j], 0, 0, 0);
          acc[i][j] = __builtin_amdgcn_mfma_f32_16x16x32_bf16(al[i], bh[j], acc[i][j], 0, 0, 0);
          acc[i][j] = __builtin_amdgcn_mfma_f32_16x16x32_bf16(al[i], bl[j], acc[i][j], 0, 0, 0);
        }
    }

    wfa = nfa;
    wfb = nfb;
  }

  // ---- epilogue: two-half LDS staging (32 KB) + LIF t-scan, s1 as i8 ----
  float* hl = (float*)smem;               // [64][128]
  const int c = tid & 127;
  const float bv = bias[bn + c];
  float v = 0.0f;
  __syncthreads();
#pragma unroll
  for (int half = 0; half < 2; ++half) {
    if (wm == half * 64) {
#pragma unroll
      for (int i = 0; i < 4; ++i)
#pragma unroll
        for (int j = 0; j < 4; ++j) {
          int col = wn + j * 16 + (lane & 15);
#pragma unroll
          for (int r = 0; r < 4; ++r) {
            int lrow = i * 16 + (lane >> 4) * 4 + r;
            hl[lrow * 128 + col] = acc[i][j][r];
          }
        }
    }
    __syncthreads();
    if (tid < 128) {
      for (int tt = 0; tt < 64; ++tt) {
        float h = hl[tt * 128 + c] + bv;
        v = 0.9f * v + h;
        i8 sp = 0;
        if (v > 1.0f) { sp = 1; v -= 1.0f; }
        s1out[(size_t)(bm + half * 64 + tt) * H_ + bn + c] = sp;
      }
    }
    __syncthreads();
  }
}

// ---------- GEMM2: i8 3-plane, two-loop, A-DIRECT (global->reg frags) ----------
// R19: counter arithmetic shows gemm2 is LDS-PIPE-bound, not MFMA-bound:
//   LDS/CU = staging writes ~5MB (17us) + 10240 ds_read_b128 (51us) = 68us
//   vs MFMA floor 52us. R13's 90us = 76% of the LDS ceiling — which is why
//   every schedule permutation (R14-R18) failed to beat it.
// Fix: the A operand (s1) skips LDS entirely. A 16x16x64 i8 A-fragment is
//   16 contiguous bytes at A[row(lane&15)][k + 16*(lane>>4)] — loadable as
//   a coalesced per-lane global_load_dwordx4 straight into frag registers
//   (L1/L2-served; same global bytes as staging moved before).
// New LDS total ~41us < MFMA 52us -> MFMA becomes the binding pipe.
// Structure: R13's measured-best serial stage pattern, both loops BK=128:
//   {sync; GLD B-planes; issue A-frag loads; sync(drain); 2 ksteps compute}.
// Register audit (the R15-R17 spill lesson): <=2 plane-accs per loop.
//   Loop A: AGPR 128 (acc1,acc2) + VGPR a32+b32+addr ~100 = ~230 <= 256 OK
//   Loop B: AGPR 128 (facc,acc0) + VGPR a32+b16+addr ~90  = ~220 <= 256 OK
// Math identical: facc = 2^-28*((Σc1<<8)+Σc2) + 2^-12*Σc0, exact ints.
#define G2_GLD(srcp, ldsp)                                                  \
  __builtin_amdgcn_global_load_lds(                                         \
      (const __attribute__((address_space(1))) unsigned int*)(srcp),        \
      (__attribute__((address_space(3))) unsigned int*)(ldsp), 16, 0, 0)

__global__ __launch_bounds__(256, 2) void gemm2_i8(
    const i8* __restrict__ A,
    const i8* __restrict__ P0, const i8* __restrict__ P1,
    const i8* __restrict__ P2,
    const float* __restrict__ bias, float* __restrict__ s2out) {
  __shared__ __align__(16) char smem[32768];
  i8* sB1 = (i8*)smem;                   // loop A: P1 tile 16K
  i8* sB2 = (i8*)(smem + 16384);         // loop A: P2 tile 16K
  i8* sB0 = (i8*)smem;                   // loop B: P0 tile 16K (reuse)

  const int tid  = threadIdx.x;
  const int lane = tid & 63;
  const int wid  = tid >> 6;           // 0..3
  const int wm   = (wid >> 1) * 64;    // 0,64
  const int wn   = (wid & 1) * 64;     // 0,64
  const int bid  = blockIdx.y * 32 + blockIdx.x;
  int bnI, bmI;
  xcd_swizzle(bid, bnI, bmI);
  const int bm = bmI * 128;
  const int bn = bnI * 128;

  const int q16  = (lane >> 4) * 16;
  const int r15  = lane & 15;
  const int rswb = (lane & 7) * 16;

  // B staging addressing (R13-verbatim, HW-validated)
  const int sdstB = (tid & 7) * 16;
  const int scolB = (((tid & 7) ^ ((tid >> 3) & 7)) * 16);

  // A-direct fragment base: lane reads 16B at row (bm+wm+i*16+r15), col kt+ks*64+q16
  const size_t aBase = (size_t)(bm + wm + r15) * H_ + q16;

  f32x4 facc[4][4];

  // ======== Loop A: planes 1+2, BK=128, stage P1+P2 only ========
  {
    i32x4 acc1[4][4], acc2[4][4];
#pragma unroll
    for (int i = 0; i < 4; ++i)
#pragma unroll
      for (int j = 0; j < 4; ++j) {
        acc1[i][j] = (i32x4){0, 0, 0, 0};
        acc2[i][j] = (i32x4){0, 0, 0, 0};
      }

#pragma unroll 1
    for (int kt = 0; kt < H_; kt += 128) {
      __syncthreads();                  // prev tile's readers done
#pragma unroll
      for (int l = 0; l < 4; ++l) {
        int row = l * 32 + (tid >> 3);
        int ld  = row * 128 + sdstB;
        G2_GLD(P1 + (size_t)(bn + row) * H_ + kt + scolB, sB1 + ld);
        G2_GLD(P2 + (size_t)(bn + row) * H_ + kt + scolB, sB2 + ld);
      }
      // A-direct frag loads for this tile (2 ksteps x 4 row-frags)
      i32x4 a[2][4];
#pragma unroll
      for (int ks = 0; ks < 2; ++ks)
#pragma unroll
        for (int i = 0; i < 4; ++i)
          a[ks][i] = *(const i32x4*)(A + aBase + (size_t)i * 16 * H_ + kt + ks * 64);
      __syncthreads();                  // drain GLDs + a-loads together

#pragma unroll
      for (int ks = 0; ks < 2; ++ks) {
        const int swz = (ks * 64 + q16) ^ rswb;
        i32x4 b1[4], b2[4];
#pragma unroll
        for (int j = 0; j < 4; ++j) {
          int ro = (wn + j * 16 + r15) * 128 + swz;
          b1[j] = *(const i32x4*)(sB1 + ro);
          b2[j] = *(const i32x4*)(sB2 + ro);
        }
        __builtin_amdgcn_s_setprio(1);
#pragma unroll
        for (int i = 0; i < 4; ++i)
#pragma unroll
          for (int j = 0; j < 4; ++j) {
            acc1[i][j] = __builtin_amdgcn_mfma_i32_16x16x64_i8(a[ks][i], b1[j], acc1[i][j], 0, 0, 0);
            acc2[i][j] = __builtin_amdgcn_mfma_i32_16x16x64_i8(a[ks][i], b2[j], acc2[i][j], 0, 0, 0);
          }
        __builtin_amdgcn_s_setprio(0);
      }
    }

    // fold exact: facc = 2^-28 * ((Σc1)<<8 + Σc2)   (|Σc1|<=2^19 -> no ovf)
#pragma unroll
    for (int i = 0; i < 4; ++i)
#pragma unroll
      for (int j = 0; j < 4; ++j)
#pragma unroll
        for (int r = 0; r < 4; ++r)
          facc[i][j][r] = 0x1p-28f * (float)((acc1[i][j][r] << 8) + acc2[i][j][r]);
  }

  // ======== Loop B: plane 0, BK=128, stage P0 only ========
  {
    i32x4 acc0[4][4];
#pragma unroll
    for (int i = 0; i < 4; ++i)
#pragma unroll
      for (int j = 0; j < 4; ++j) acc0[i][j] = (i32x4){0, 0, 0, 0};

#pragma unroll 1
    for (int kt = 0; kt < H_; kt += 128) {
      __syncthreads();
#pragma unroll
      for (int l = 0; l < 4; ++l) {
        int row = l * 32 + (tid >> 3);
        int ld  = row * 128 + sdstB;
        G2_GLD(P0 + (size_t)(bn + row) * H_ + kt + scolB, sB0 + ld);
      }
      i32x4 a[2][4];
#pragma unroll
      for (int ks = 0; ks < 2; ++ks)
#pragma unroll
        for (int i = 0; i < 4; ++i)
          a[ks][i] = *(const i32x4*)(A + aBase + (size_t)i * 16 * H_ + kt + ks * 64);
      __syncthreads();

#pragma unroll
      for (int ks = 0; ks < 2; ++ks) {
        const int swz = (ks * 64 + q16) ^ rswb;
        i32x4 b[4];
#pragma unroll
        for (int j = 0; j < 4; ++j)
          b[j] = *(const i32x4*)(sB0 + (wn + j * 16 + r15) * 128 + swz);
        __builtin_amdgcn_s_setprio(1);
#pragma unroll
        for (int i = 0; i < 4; ++i)
#pragma unroll
          for (int j = 0; j < 4; ++j)
            acc0[i][j] = __builtin_amdgcn_mfma_i32_16x16x64_i8(a[ks][i], b[j], acc0[i][j], 0, 0, 0);
        __builtin_amdgcn_s_setprio(0);
      }
    }
#pragma unroll
    for (int i = 0; i < 4; ++i)
#pragma unroll
      for (int j = 0; j < 4; ++j)
#pragma unroll
        for (int r = 0; r < 4; ++r)
          facc[i][j][r] += 0x1p-12f * (float)acc0[i][j][r];
  }

  // ---- epilogue: two-half staging (32 KB) + LIF t-scan ----
  float* hl = (float*)smem;               // [64][128]
  const int c = tid & 127;
  const float bv = bias[bn + c];
  float v = 0.0f, cnt = 0.0f;
  __syncthreads();
#pragma unroll
  for (int half = 0; half < 2; ++half) {
    if (wm == half * 64) {
#pragma unroll
      for (int i = 0; i < 4; ++i)
#pragma unroll
        for (int j = 0; j < 4; ++j) {
          int col = wn + j * 16 + (lane & 15);
#pragma unroll
          for (int r = 0; r < 4; ++r) {
            int lrow = i * 16 + (lane >> 4) * 4 + r;
            hl[lrow * 128 + col] = facc[i][j][r];
          }
        }
    }
    __syncthreads();
    if (tid < 128) {
      for (int tt = 0; tt < 64; ++tt) {
        float h = hl[tt * 128 + c] + bv;
        v = 0.9f * v + h;
        if (v > 1.0f) { cnt += 1.0f; v -= 1.0f; }
      }
    }
    __syncthreads();
  }
  if (tid < 128) s2out[(size_t)bmI * H_ + bn + c] = cnt;
}

// ---------- readout: out[b,o] = s2sum[b,:] . w3[o,:] + T*b3[o] ----------
__global__ void out_gemm_kernel(const float* __restrict__ s2sum,
                                const float* __restrict__ w3,
                                const float* __restrict__ b3,
                                float* __restrict__ out) {
  int o = blockIdx.x;
  int lane = threadIdx.x;
  float acc[B_];
#pragma unroll
  for (int b = 0; b < B_; ++b) acc[b] = 0.f;
  const float* wrow = w3 + (size_t)o * H_;
  for (int i = 0; i < H_ / 64; ++i) {
    float w = wrow[i * 64 + lane];
#pragma unroll
    for (int b = 0; b < B_; ++b)
      acc[b] += w * s2sum[b * H_ + i * 64 + lane];
  }
#pragma unroll
  for (int b = 0; b < B_; ++b) {
    float v = acc[b];
#pragma unroll
    for (int off = 32; off > 0; off >>= 1) v += __shfl_xor(v, off);
    if (lane == b) out[b * OUT_ + o] = v + (float)T_ * b3[o];
  }
}

// ---------- launch ----------
extern "C" void kernel_launch(void* const* d_in, const int* in_sizes, int n_in,
                              void* d_out, int out_size, void* d_ws, size_t ws_size,
                              hipStream_t stream) {
  const float* x  = (const float*)d_in[0];
  const float* w1 = (const float*)d_in[1];
  const float* b1 = (const float*)d_in[2];
  const float* w2 = (const float*)d_in[3];
  const float* b2 = (const float*)d_in[4];
  const float* w3 = (const float*)d_in[5];
  const float* b3 = (const float*)d_in[6];
  float* out = (float*)d_out;

  // workspace (80.25 MiB):
  //   [0,8M) s1 i8 | [8M,12M) x_hi | [12M,16M) x_lo | [16M,24M) w1_hi
  //   [24M,32M) w1_lo | [32M,48M) w2p0 | [48M,64M) w2p1 | [64M,80M) w2p2
  //   [80M,+256K) s2sum
  char* ws = (char*)d_ws;
  i8*    s1    = (i8*)(ws);
  u16*   x_hi  = (u16*)(ws + 8388608);
  u16*   x_lo  = (u16*)(ws + 12582912);
  u16*   w1_hi = (u16*)(ws + 16777216);
  u16*   w1_lo = (u16*)(ws + 25165824);
  i8*    w2p0  = (i8*)(ws + 33554432);
  i8*    w2p1  = (i8*)(ws + 50331648);
  i8*    w2p2  = (i8*)(ws + 67108864);
  float* s2sum = (float*)(ws + 83886080);

  // 1) split x, w1 only (48 MB traffic, ~8 us)
  split_xw1_kernel<<<1024, 256, 0, stream>>>((const float4*)x, (const float4*)w1,
                                             x_hi, x_lo, w1_hi, w1_lo);

  dim3 g1(H_ / 128, M_ / 128);  // (32, 16) = 512 blocks
  // 2) GEMM1 + fused rec1 + pipelined woven w2 split, XCD-swizzled
  gemm1_rec<<<g1, 256, 0, stream>>>(x_hi, x_lo, w1_hi, w1_lo, b1, s1,
                                    (const float4*)w2, w2p0, w2p1, w2p2);

  // 3) GEMM2 + fused rec2: two-loop, A-direct (global->reg frags)
  gemm2_i8<<<g1, 256, 0, stream>>>(s1, w2p0, w2p1, w2p2, b2, s2sum);

  // 4) readout
  out_gemm_kernel<<<OUT_, 64, 0, stream>>>(s2sum, w3, b3, out);
}

// Round 7
// 184.272 us; speedup vs baseline: 1.3444x; 1.3444x over previous
//
#include <hip/hip_runtime.h>
#include <hip/hip_bf16.h>

#define B_   16
#define T_   128
#define IN_  1024
#define H_   4096
#define OUT_ 1024
#define M_   (B_ * T_)   // 2048 rows = (b*T + t)

typedef __attribute__((ext_vector_type(8))) short short8;
typedef __attribute__((ext_vector_type(4))) float f32x4;
typedef __attribute__((ext_vector_type(4))) int i32x4;
typedef __attribute__((ext_vector_type(4))) unsigned short u16x4;
typedef unsigned short u16;
typedef signed char i8;

// ---------- helpers ----------
__device__ inline u16 f2bf_rne(float f) {
  unsigned u = __float_as_uint(f);
  unsigned r = u + 0x7FFFu + ((u >> 16) & 1u);
  return (u16)(r >> 16);
}
__device__ inline float bf2f(u16 s) {
  return __uint_as_float(((unsigned)s) << 16);
}
__device__ inline int pack4(int a, int b, int c, int d) {
  return (a & 255) | ((b & 255) << 8) | ((c & 255) << 16) | ((d & 255) << 24);
}

// XCD-aware 2D-chunked bijective swizzle (T1) for the 512-block gemm1 grid.
__device__ inline void xcd_swizzle(int bid0, int& bnI, int& bmI) {
  const int xcd = bid0 & 7;
  const int loc = bid0 >> 3;           // 0..63 within XCD
  bnI = (xcd & 3) * 8 + (loc & 7);
  bmI = (xcd >> 2) * 8 + (loc >> 3);
}

#define NX_  (M_ * IN_)
#define NW1_ (H_ * IN_)
#define NW2_ (H_ * H_)

__device__ inline void split4bf(const float4 f, u16* __restrict__ hi,
                                u16* __restrict__ lo, size_t e) {
  u16x4 h, l;
  h.x = f2bf_rne(f.x); l.x = f2bf_rne(f.x - bf2f(h.x));
  h.y = f2bf_rne(f.y); l.y = f2bf_rne(f.y - bf2f(h.y));
  h.z = f2bf_rne(f.z); l.z = f2bf_rne(f.z - bf2f(h.z));
  h.w = f2bf_rne(f.w); l.w = f2bf_rne(f.w - bf2f(h.w));
  *(u16x4*)(hi + e) = h;
  *(u16x4*)(lo + e) = l;
}

__device__ inline void splitw2_1(float w, int& c0, int& c1, int& c2) {
  int wf = __float2int_rn(w * 268435456.0f);  // 2^28 (exact: wf == c0<<16 + c1<<8 + c2)
  c0 = (wf + 32768) >> 16;
  int r0 = wf - (c0 << 16);
  if (r0 >= 32640) { c0 += 1; r0 -= 65536; }
  c1 = (r0 + 128) >> 8;
  c2 = r0 - (c1 << 8);
}

// ---------- split x, w1 only (w2 split is woven into gemm1) ----------
__global__ void split_xw1_kernel(const float4* __restrict__ x,
                                 const float4* __restrict__ w1,
                                 u16* __restrict__ xh, u16* __restrict__ xl,
                                 u16* __restrict__ w1h, u16* __restrict__ w1l) {
  const int total4 = (NX_ + NW1_) / 4;
  for (int i = blockIdx.x * blockDim.x + threadIdx.x; i < total4;
       i += gridDim.x * blockDim.x) {
    if (i < NX_ / 4) {
      split4bf(x[i], xh, xl, (size_t)i * 4);
    } else {
      int j = i - NX_ / 4;
      split4bf(w1[j], w1h, w1l, (size_t)j * 4);
    }
  }
}

// ---------- GEMM1: FUSED 4-combo bf16 (16x16x32, BK=64) + rec1 -> s1 (i8) ----------
// (unchanged — isolate the gemm2 merged-tile change)
#define BK1 64

__global__ __launch_bounds__(256, 2) void gemm1_rec(
    const u16* __restrict__ Ah, const u16* __restrict__ Al,
    const u16* __restrict__ Bh, const u16* __restrict__ Bl,
    const float* __restrict__ bias, i8* __restrict__ s1out,
    const float4* __restrict__ w2src,
    i8* __restrict__ p0, i8* __restrict__ p1, i8* __restrict__ p2) {
  __shared__ __align__(16) char smem[65536];   // sAh|sAl|sBh|sBl 16K each; epilogue reuses [0,32K)
  u16* sAh = (u16*)smem;
  u16* sAl = (u16*)(smem + 16384);
  u16* sBh = (u16*)(smem + 32768);
  u16* sBl = (u16*)(smem + 49152);

  const int tid  = threadIdx.x;
  const int lane = tid & 63;
  const int wid  = tid >> 6;
  const int wm   = (wid >> 1) * 64;
  const int wn   = (wid & 1) * 64;
  const int bid  = blockIdx.y * 32 + blockIdx.x;   // flat id: w2-slice owner
  int bnI, bmI;
  xcd_swizzle(bid, bnI, bmI);
  const int bm = bmI * 128;
  const int bn = bnI * 128;

  const int sdst = (tid & 7) * 8;                          // linear LDS dest slot (elems)
  const int scol = (((tid & 7) ^ ((tid >> 3) & 7)) * 8);   // inverse-swizzled src col
  const int q8   = (lane >> 4) * 8;
  const int rsw  = (lane & 7) * 8;                         // row&7 == lane&7 swizzle

  f32x4 acc[4][4];
#pragma unroll
  for (int i = 0; i < 4; ++i)
#pragma unroll
    for (int j = 0; j < 4; ++j) acc[i][j] = (f32x4){0.f, 0.f, 0.f, 0.f};

  // woven-split pipeline prologue: tile 0's slice into regs
  const int wbase = bid * 8192 + tid * 2;
  float4 wfa = w2src[wbase];
  float4 wfb = w2src[wbase + 1];

#pragma unroll 1
  for (int it = 0; it < IN_ / BK1; ++it) {   // 16 k-tiles
    const int kt = it * BK1;
    __syncthreads();   // bar1: wf prefetch + stores from prev iter long done
#pragma unroll
    for (int l = 0; l < 4; ++l) {
      int row = l * 32 + (tid >> 3);
      size_t ga = (size_t)(bm + row) * IN_ + kt + scol;
      size_t gb = (size_t)(bn + row) * IN_ + kt + scol;
      int ld = row * BK1 + sdst;
      __builtin_amdgcn_global_load_lds(
          (const __attribute__((address_space(1))) unsigned int*)(Ah + ga),
          (__attribute__((address_space(3))) unsigned int*)(&sAh[ld]), 16, 0, 0);
      __builtin_amdgcn_global_load_lds(
          (const __attribute__((address_space(1))) unsigned int*)(Al + ga),
          (__attribute__((address_space(3))) unsigned int*)(&sAl[ld]), 16, 0, 0);
      __builtin_amdgcn_global_load_lds(
          (const __attribute__((address_space(1))) unsigned int*)(Bh + gb),
          (__attribute__((address_space(3))) unsigned int*)(&sBh[ld]), 16, 0, 0);
      __builtin_amdgcn_global_load_lds(
          (const __attribute__((address_space(1))) unsigned int*)(Bl + gb),
          (__attribute__((address_space(3))) unsigned int*)(&sBl[ld]), 16, 0, 0);
    }
    __syncthreads();   // bar2: drains ONLY L2-resident staging loads now

    // prefetch NEXT tile's wf slice (covered by the MFMA phase below)
    const int nit = (it + 1 < 16) ? it + 1 : 15;
    float4 nfa = w2src[wbase + nit * 512];
    float4 nfb = w2src[wbase + nit * 512 + 1];

    // convert + store CURRENT tile's wf (independent of MFMA; drains in bg)
    {
      const int sbase = bid * 8192 + it * 512 + tid * 2;
#pragma unroll
      for (int u = 0; u < 2; ++u) {
        float4 f = u ? wfb : wfa;
        int a0, a1, a2, b0, b1, b2, c0, c1, c2, d0, d1, d2;
        splitw2_1(f.x, a0, a1, a2);
        splitw2_1(f.y, b0, b1, b2);
        splitw2_1(f.z, c0, c1, c2);
        splitw2_1(f.w, d0, d1, d2);
        size_t e = (size_t)(sbase + u) * 4;
        *(int*)(p0 + e) = pack4(a0, b0, c0, d0);
        *(int*)(p1 + e) = pack4(a1, b1, c1, d1);
        *(int*)(p2 + e) = pack4(a2, b2, c2, d2);
      }
    }

#pragma unroll
    for (int ks = 0; ks < BK1; ks += 32) {
      const int swz = (ks + q8) ^ rsw;
      short8 ah[4], al[4], bh[4], bl[4];
#pragma unroll
      for (int i = 0; i < 4; ++i) {
        int ro = (wm + i * 16 + (lane & 15)) * BK1 + swz;
        ah[i] = *(const short8*)&sAh[ro];
        al[i] = *(const short8*)&sAl[ro];
      }
#pragma unroll
      for (int j = 0; j < 4; ++j) {
        int ro = (wn + j * 16 + (lane & 15)) * BK1 + swz;
        bh[j] = *(const short8*)&sBh[ro];
        bl[j] = *(const short8*)&sBl[ro];
      }
#pragma unroll
      for (int i = 0; i < 4; ++i)
#pragma unroll
        for (int j = 0; j < 4; ++j) {
          acc[i][j] = __builtin_amdgcn_mfma_f32_16x16x32_bf16(ah[i], bh[j], acc[i][j], 0, 0, 0);
          acc[i][j] = __builtin_amdgcn_mfma_f32_16x16x32_bf16(ah[i], bl[j], acc[i][j], 0, 0, 0);
          acc[i][j] = __builtin_amdgcn_mfma_f32_16x16x32_bf16(al[i], bh[j], acc[i][j], 0, 0, 0);
          acc[i][j] = __builtin_amdgcn_mfma_f32_16x16x32_bf16(al[i], bl[j], acc[i][j], 0, 0, 0);
        }
    }

    wfa = nfa;
    wfb = nfb;
  }

  // ---- epilogue: two-half LDS staging (32 KB) + LIF t-scan, s1 as i8 ----
  float* hl = (float*)smem;               // [64][128]
  const int c = tid & 127;
  const float bv = bias[bn + c];
  float v = 0.0f;
  __syncthreads();
#pragma unroll
  for (int half = 0; half < 2; ++half) {
    if (wm == half * 64) {
#pragma unroll
      for (int i = 0; i < 4; ++i)
#pragma unroll
        for (int j = 0; j < 4; ++j) {
          int col = wn + j * 16 + (lane & 15);
#pragma unroll
          for (int r = 0; r < 4; ++r) {
            int lrow = i * 16 + (lane >> 4) * 4 + r;
            hl[lrow * 128 + col] = acc[i][j][r];
          }
        }
    }
    __syncthreads();
    if (tid < 128) {
      for (int tt = 0; tt < 64; ++tt) {
        float h = hl[tt * 128 + c] + bv;
        v = 0.9f * v + h;
        i8 sp = 0;
        if (v > 1.0f) { sp = 1; v -= 1.0f; }
        s1out[(size_t)(bm + half * 64 + tt) * H_ + bn + c] = sp;
      }
    }
    __syncthreads();
  }
}

// ---------- GEMM2: i8 3-plane MERGED K-loop, 128x64 tile (96 acc regs) ----------
// R20: the register wall (192 acc regs for 3 planes at 64x64/wave) forced
// R13's two-loop form (A staged twice, 64 drain events, 40 GLD/thread/256K).
// Fix the wall GEOMETRICALLY: block tile 128x64, wave tile 64x32 ->
// 3 plane-accs = 3*(4*2*4) = 96 regs. ONE merged loop:
//   - 32 tiles (halved drain events), 10 staging GLD/thread/tile (halved),
//   - A staged once, LDS reads 10 b128/kstep/wave (-37%),
//   - exact R13 serial pattern (sync; stage; sync; compute) — the only
//     structure that measured well (R14-R19 all regressed).
// LDS 40K/block: A[128][128B] 16K | P1 8K | P2 8K | P0 8K (single buffer).
// Register audit: 96 acc + a16 + b24 + addr ~25 = ~160 <= 256 (big slack).
// Math identical: facc = 2^-28*((S1<<8)+S2) + 2^-12*S0, exact ints.
#define G2_GLD(srcp, ldsp)                                                  \
  __builtin_amdgcn_global_load_lds(                                         \
      (const __attribute__((address_space(1))) unsigned int*)(srcp),        \
      (__attribute__((address_space(3))) unsigned int*)(ldsp), 16, 0, 0)

__global__ __launch_bounds__(256, 2) void gemm2_i8(
    const i8* __restrict__ A,
    const i8* __restrict__ P0, const i8* __restrict__ P1,
    const i8* __restrict__ P2,
    const float* __restrict__ bias, float* __restrict__ s2out) {
  __shared__ __align__(16) char smem[40960];
  i8* sA  = (i8*)smem;                   // A tile   [128][128B] 16K
  i8* sB1 = (i8*)(smem + 16384);         // P1 tile  [64][128B]   8K
  i8* sB2 = (i8*)(smem + 24576);         // P2 tile  [64][128B]   8K
  i8* sB0 = (i8*)(smem + 32768);         // P0 tile  [64][128B]   8K

  const int tid  = threadIdx.x;
  const int lane = tid & 63;
  const int wid  = tid >> 6;           // 0..3
  const int wm   = (wid >> 1) * 64;    // 0,64   (rows)
  const int wn   = (wid & 1) * 32;     // 0,32   (cols)

  // bijective XCD swizzle for 1024 blocks: 16 bmI x 64 bnI
  const int bid = blockIdx.x;
  const int xcd = bid & 7, loc = bid >> 3;     // loc 0..127
  const int bnI = xcd * 8 + (loc & 7);         // 0..63
  const int bmI = loc >> 3;                    // 0..15
  const int bm = bmI * 128, bn = bnI * 64;

  const int q16  = (lane >> 4) * 16;
  const int r15  = lane & 15;
  const int rswb = (lane & 7) * 16;

  // staging addressing (R13-verbatim, HW-validated)
  const int sdstB = (tid & 7) * 16;
  const int scolB = (((tid & 7) ^ ((tid >> 3) & 7)) * 16);
  const int strow = tid >> 3;                  // 0..31

  i32x4 acc0[4][2], acc1[4][2], acc2[4][2];
#pragma unroll
  for (int i = 0; i < 4; ++i)
#pragma unroll
    for (int j = 0; j < 2; ++j) {
      acc0[i][j] = (i32x4){0, 0, 0, 0};
      acc1[i][j] = (i32x4){0, 0, 0, 0};
      acc2[i][j] = (i32x4){0, 0, 0, 0};
    }

#pragma unroll 1
  for (int kt = 0; kt < H_; kt += 128) {   // 32 k-tiles
    __syncthreads();                        // prev tile's readers done
    // stage A: 128 rows (4 GLDs)
#pragma unroll
    for (int l = 0; l < 4; ++l) {
      int row = l * 32 + strow;
      G2_GLD(A + (size_t)(bm + row) * H_ + kt + scolB, sA + row * 128 + sdstB);
    }
    // stage P1,P2,P0: 64 rows each (2 GLDs each)
#pragma unroll
    for (int l = 0; l < 2; ++l) {
      int row = l * 32 + strow;
      int ld  = row * 128 + sdstB;
      size_t g = (size_t)(bn + row) * H_ + kt + scolB;
      G2_GLD(P1 + g, sB1 + ld);
      G2_GLD(P2 + g, sB2 + ld);
      G2_GLD(P0 + g, sB0 + ld);
    }
    __syncthreads();                        // drain all staging

#pragma unroll
    for (int ks = 0; ks < 2; ++ks) {
      const int swz = (ks * 64 + q16) ^ rswb;
      i32x4 a[4], b1[2], b2[2], b0[2];
#pragma unroll
      for (int i = 0; i < 4; ++i)
        a[i] = *(const i32x4*)(sA + (wm + i * 16 + r15) * 128 + swz);
#pragma unroll
      for (int j = 0; j < 2; ++j) {
        int ro = (wn + j * 16 + r15) * 128 + swz;
        b1[j] = *(const i32x4*)(sB1 + ro);
        b2[j] = *(const i32x4*)(sB2 + ro);
        b0[j] = *(const i32x4*)(sB0 + ro);
      }
#pragma unroll
      for (int i = 0; i < 4; ++i)
#pragma unroll
        for (int j = 0; j < 2; ++j) {
          acc1[i][j] = __builtin_amdgcn_mfma_i32_16x16x64_i8(a[i], b1[j], acc1[i][j], 0, 0, 0);
          acc2[i][j] = __builtin_amdgcn_mfma_i32_16x16x64_i8(a[i], b2[j], acc2[i][j], 0, 0, 0);
          acc0[i][j] = __builtin_amdgcn_mfma_i32_16x16x64_i8(a[i], b0[j], acc0[i][j], 0, 0, 0);
        }
    }
  }

  // fold exact: facc = 2^-28*((S1<<8)+S2) + 2^-12*S0  (|S1|<=2^19 -> no ovf)
  f32x4 facc[4][2];
#pragma unroll
  for (int i = 0; i < 4; ++i)
#pragma unroll
    for (int j = 0; j < 2; ++j)
#pragma unroll
      for (int r = 0; r < 4; ++r)
        facc[i][j][r] = 0x1p-28f * (float)((acc1[i][j][r] << 8) + acc2[i][j][r]) +
                        0x1p-12f * (float)acc0[i][j][r];

  // ---- epilogue: two-half staging [64][64] + LIF t-scan over 128 t ----
  float* hl = (float*)smem;               // [64][64]
  const int c = tid & 63;
  const float bv = bias[bn + c];
  float v = 0.0f, cnt = 0.0f;
  __syncthreads();
#pragma unroll
  for (int half = 0; half < 2; ++half) {
    if (wm == half * 64) {
#pragma unroll
      for (int i = 0; i < 4; ++i)
#pragma unroll
        for (int j = 0; j < 2; ++j) {
          int col = wn + j * 16 + (lane & 15);
#pragma unroll
          for (int r = 0; r < 4; ++r) {
            int lrow = i * 16 + (lane >> 4) * 4 + r;
            hl[lrow * 64 + col] = facc[i][j][r];
          }
        }
    }
    __syncthreads();
    if (tid < 64) {
      for (int tt = 0; tt < 64; ++tt) {
        float h = hl[tt * 64 + c] + bv;
        v = 0.9f * v + h;
        if (v > 1.0f) { cnt += 1.0f; v -= 1.0f; }
      }
    }
    __syncthreads();
  }
  if (tid < 64) s2out[(size_t)bmI * H_ + bn + c] = cnt;
}

// ---------- readout: out[b,o] = s2sum[b,:] . w3[o,:] + T*b3[o] ----------
__global__ void out_gemm_kernel(const float* __restrict__ s2sum,
                                const float* __restrict__ w3,
                                const float* __restrict__ b3,
                                float* __restrict__ out) {
  int o = blockIdx.x;
  int lane = threadIdx.x;
  float acc[B_];
#pragma unroll
  for (int b = 0; b < B_; ++b) acc[b] = 0.f;
  const float* wrow = w3 + (size_t)o * H_;
  for (int i = 0; i < H_ / 64; ++i) {
    float w = wrow[i * 64 + lane];
#pragma unroll
    for (int b = 0; b < B_; ++b)
      acc[b] += w * s2sum[b * H_ + i * 64 + lane];
  }
#pragma unroll
  for (int b = 0; b < B_; ++b) {
    float v = acc[b];
#pragma unroll
    for (int off = 32; off > 0; off >>= 1) v += __shfl_xor(v, off);
    if (lane == b) out[b * OUT_ + o] = v + (float)T_ * b3[o];
  }
}

// ---------- launch ----------
extern "C" void kernel_launch(void* const* d_in, const int* in_sizes, int n_in,
                              void* d_out, int out_size, void* d_ws, size_t ws_size,
                              hipStream_t stream) {
  const float* x  = (const float*)d_in[0];
  const float* w1 = (const float*)d_in[1];
  const float* b1 = (const float*)d_in[2];
  const float* w2 = (const float*)d_in[3];
  const float* b2 = (const float*)d_in[4];
  const float* w3 = (const float*)d_in[5];
  const float* b3 = (const float*)d_in[6];
  float* out = (float*)d_out;

  // workspace (80.25 MiB):
  //   [0,8M) s1 i8 | [8M,12M) x_hi | [12M,16M) x_lo | [16M,24M) w1_hi
  //   [24M,32M) w1_lo | [32M,48M) w2p0 | [48M,64M) w2p1 | [64M,80M) w2p2
  //   [80M,+256K) s2sum
  char* ws = (char*)d_ws;
  i8*    s1    = (i8*)(ws);
  u16*   x_hi  = (u16*)(ws + 8388608);
  u16*   x_lo  = (u16*)(ws + 12582912);
  u16*   w1_hi = (u16*)(ws + 16777216);
  u16*   w1_lo = (u16*)(ws + 25165824);
  i8*    w2p0  = (i8*)(ws + 33554432);
  i8*    w2p1  = (i8*)(ws + 50331648);
  i8*    w2p2  = (i8*)(ws + 67108864);
  float* s2sum = (float*)(ws + 83886080);

  // 1) split x, w1 only (48 MB traffic, ~8 us)
  split_xw1_kernel<<<1024, 256, 0, stream>>>((const float4*)x, (const float4*)w1,
                                             x_hi, x_lo, w1_hi, w1_lo);

  dim3 g1(H_ / 128, M_ / 128);  // (32, 16) = 512 blocks
  // 2) GEMM1 + fused rec1 + pipelined woven w2 split, XCD-swizzled
  gemm1_rec<<<g1, 256, 0, stream>>>(x_hi, x_lo, w1_hi, w1_lo, b1, s1,
                                    (const float4*)w2, w2p0, w2p1, w2p2);

  // 3) GEMM2 + fused rec2: merged 3-plane loop, 128x64 tile
  gemm2_i8<<<dim3(1024), 256, 0, stream>>>(s1, w2p0, w2p1, w2p2, b2, s2sum);

  // 4) readout
  out_gemm_kernel<<<OUT_, 64, 0, stream>>>(s2sum, w3, b3, out);
}